// Round 1
// baseline (6207.106 us; speedup 1.0000x reference)
//
#include <hip/hip_runtime.h>
#include <hip/hip_bf16.h>

// Problem constants
#define BB    4096
#define TT    128
#define DSEQ_ 128
#define HH    256
#define DOUT_ 128
#define NEXP_ 4
static const long NUM_EDGES_ = 838860;  // int(4096*4096*0.05)

typedef _Float16 f16;
typedef _Float16 f16x8 __attribute__((ext_vector_type(8)));
typedef float    f32x4 __attribute__((ext_vector_type(4)));

// ---------------------------------------------------------------------------
// Weight packing: Wp[n][k], n = 4*u + g  (g: 0=r, 1=z, 2=i_n, 3=h_n)
// k < Din  -> Wih rows {u, 256+u, 512+u}; k >= Din -> Whh (g==2 zero, g==3 = n-gate h part)
// ---------------------------------------------------------------------------
__global__ void pack_weights_kernel(const float* __restrict__ Wih,
                                    const float* __restrict__ Whh,
                                    f16* __restrict__ Wp, int Din)
{
    const int K = Din + HH;
    const int total = 1024 * K;
    for (int idx = blockIdx.x * 256 + threadIdx.x; idx < total; idx += gridDim.x * 256) {
        int n = idx / K, k = idx % K;
        int u = n >> 2, g = n & 3;
        float v = 0.f;
        if (k < Din) {
            if (g == 0)      v = Wih[(long)u * Din + k];
            else if (g == 1) v = Wih[(long)(256 + u) * Din + k];
            else if (g == 2) v = Wih[(long)(512 + u) * Din + k];
        } else {
            int kh = k - Din;
            if (g == 0)      v = Whh[(long)u * HH + kh];
            else if (g == 1) v = Whh[(long)(256 + u) * HH + kh];
            else if (g == 3) v = Whh[(long)(512 + u) * HH + kh];
        }
        Wp[idx] = (f16)v;
    }
}

__global__ void pack_bias_kernel(const float* __restrict__ bih,
                                 const float* __restrict__ bhh,
                                 float* __restrict__ bias)
{
    int n = blockIdx.x * 256 + threadIdx.x;
    if (n >= 1024) return;
    int u = n >> 2, g = n & 3;
    float v;
    if (g == 0)      v = bih[u] + bhh[u];
    else if (g == 1) v = bih[256 + u] + bhh[256 + u];
    else if (g == 2) v = bih[512 + u];
    else             v = bhh[512 + u];
    bias[n] = v;
}

// ---------------------------------------------------------------------------
// GRU superstep: blockIdx.z==0 -> layer0 at t0, blockIdx.z==1 -> layer1 at t1.
// One packed GEMM (4096 x K) @ (K x 1024) in f16 MFMA + fused gate epilogue.
// ---------------------------------------------------------------------------
__global__ __launch_bounds__(256) void gru_superstep(
    const f16* __restrict__ Wp0, const float* __restrict__ bias0,
    const float* __restrict__ xseq,
    const f16* __restrict__ h1_in, f16* __restrict__ h1_out, int t0,
    const f16* __restrict__ Wp1, const float* __restrict__ bias1,
    const f16* __restrict__ h1_x,
    const f16* __restrict__ h2_in, f16* __restrict__ h2_out, int t1)
{
    const int layer = blockIdx.z;
    if (layer == 0 && t0 >= TT) return;
    if (layer == 1 && t1 < 0) return;

    const f16* Wp; const float* bias;
    const f16* ax16 = nullptr;
    const f16* hprev; f16* hout;
    int xc, K; long xstride = 0, xoff = 0;
    if (layer == 0) {
        Wp = Wp0; bias = bias0; xc = DSEQ_; K = DSEQ_ + HH;
        xstride = (long)TT * DSEQ_; xoff = (long)t0 * DSEQ_;
        hprev = h1_in; hout = h1_out;
    } else {
        Wp = Wp1; bias = bias1; ax16 = h1_x; xc = HH; K = HH + HH;
        hprev = h2_in; hout = h2_out;
    }

    __shared__ f16 As[128 * 32];  // A tile [m][k]
    __shared__ f16 Bs[128 * 32];  // B^T tile [n][k]

    const int tid  = threadIdx.x;
    const int srow = tid >> 1;            // 0..127 staging row
    const int sc0  = (tid & 1) * 16;      // 0 or 16
    const long m0  = (long)blockIdx.x * 128;
    const int  n0  = blockIdx.y * 128;

    const int wave = tid >> 6, lane = tid & 63;
    const int wm = wave >> 1, wn = wave & 1;
    const int quad = lane >> 4, l15 = lane & 15;

    f32x4 acc[4][4];
#pragma unroll
    for (int i = 0; i < 4; i++)
#pragma unroll
        for (int j = 0; j < 4; j++) acc[i][j] = (f32x4){0.f, 0.f, 0.f, 0.f};

    const int nchunks = K >> 5;
    for (int kc = 0; kc < nchunks; kc++) {
        const int k0 = kc << 5;
        __syncthreads();
        {   // A tile: [x_t | h_prev]
            int kg = k0 + sc0;
            f16* dst = &As[srow * 32 + sc0];
            if (kg < xc) {
                if (layer == 0) {
                    const float* p = xseq + (m0 + srow) * xstride + xoff + kg;
#pragma unroll
                    for (int j = 0; j < 16; j += 4) {
                        float4 v = *(const float4*)(p + j);
                        dst[j] = (f16)v.x; dst[j + 1] = (f16)v.y;
                        dst[j + 2] = (f16)v.z; dst[j + 3] = (f16)v.w;
                    }
                } else {
                    const f16* p = ax16 + (m0 + srow) * HH + kg;
                    *(float4*)dst       = *(const float4*)p;
                    *(float4*)(dst + 8) = *(const float4*)(p + 8);
                }
            } else {
                const f16* p = hprev + (m0 + srow) * HH + (kg - xc);
                *(float4*)dst       = *(const float4*)p;
                *(float4*)(dst + 8) = *(const float4*)(p + 8);
            }
        }
        {   // B tile (pre-transposed weights Wp[n][k])
            const f16* p = Wp + (long)(n0 + srow) * K + k0 + sc0;
            f16* dst = &Bs[srow * 32 + sc0];
            *(float4*)dst       = *(const float4*)p;
            *(float4*)(dst + 8) = *(const float4*)(p + 8);
        }
        __syncthreads();

        f16x8 af[4], bf[4];
#pragma unroll
        for (int i = 0; i < 4; i++)
            af[i] = *(const f16x8*)&As[(wm * 64 + i * 16 + l15) * 32 + quad * 8];
#pragma unroll
        for (int i = 0; i < 4; i++)
            bf[i] = *(const f16x8*)&Bs[(wn * 64 + i * 16 + l15) * 32 + quad * 8];
#pragma unroll
        for (int mi = 0; mi < 4; mi++)
#pragma unroll
            for (int ni = 0; ni < 4; ni++)
                acc[mi][ni] = __builtin_amdgcn_mfma_f32_16x16x32_f16(af[mi], bf[ni], acc[mi][ni], 0, 0, 0);
    }

    // Fused gate epilogue. C layout: row = quad*4+reg, col = l15.
    // Cols interleaved 4u+{r,z,in,hn} -> gather via 4-lane shuffles.
    const long mbase = m0 + wm * 64;
    const int  nbase = n0 + wn * 64;
#pragma unroll
    for (int mi = 0; mi < 4; mi++) {
#pragma unroll
        for (int ni = 0; ni < 4; ni++) {
            const int ncol = nbase + ni * 16 + l15;
            const float bn = bias[ncol];
#pragma unroll
            for (int reg = 0; reg < 4; reg++) {
                float v = acc[mi][ni][reg] + bn;
                const int gb = lane & ~3;
                float g0 = __shfl(v, gb + 0, 64);
                float g1 = __shfl(v, gb + 1, 64);
                float g2 = __shfl(v, gb + 2, 64);
                float g3 = __shfl(v, gb + 3, 64);
                if ((lane & 3) == 0) {
                    const long mrow = mbase + mi * 16 + quad * 4 + reg;
                    const int u = ncol >> 2;
                    float hp = (float)hprev[mrow * HH + u];
                    float r = 1.f / (1.f + __expf(-g0));
                    float z = 1.f / (1.f + __expf(-g1));
                    float ng = 1.f - 2.f / (__expf(2.f * (g2 + r * g3)) + 1.f);  // tanh
                    float hn = (1.f - z) * ng + z * hp;
                    hout[mrow * HH + u] = (f16)hn;
                }
            }
        }
    }
}

// ---------------------------------------------------------------------------
// Generic fp32 GEMM: C[m,n] = act( rscale[m]*sum_k A[m,k]*B[n,k] + bias[n] )
// Requires M%64==0, N%64==0, K%16==0. Deterministic & operand-symmetric
// (used for sim = P P^T: bitwise-symmetric output).
// ---------------------------------------------------------------------------
__global__ __launch_bounds__(256) void gemm_bt_kernel(
    const float* __restrict__ A, const float* __restrict__ Bm, float* __restrict__ C,
    int M, int N, int K, const float* __restrict__ bias,
    const float* __restrict__ rscale, int act)
{
    __shared__ float As[16][65];
    __shared__ float Bs[16][65];
    const int tid = threadIdx.x;
    const long m0 = (long)blockIdx.x * 64;
    const int  n0 = blockIdx.y * 64;
    const int ty = tid >> 4, tx = tid & 15;
    const int mA = tid >> 2, kq = (tid & 3) * 4;
    float c[4][4] = {};
    for (int k0 = 0; k0 < K; k0 += 16) {
        __syncthreads();
        float4 va = *(const float4*)&A[(m0 + mA) * K + k0 + kq];
        As[kq + 0][mA] = va.x; As[kq + 1][mA] = va.y; As[kq + 2][mA] = va.z; As[kq + 3][mA] = va.w;
        float4 vb = *(const float4*)&Bm[(long)(n0 + mA) * K + k0 + kq];
        Bs[kq + 0][mA] = vb.x; Bs[kq + 1][mA] = vb.y; Bs[kq + 2][mA] = vb.z; Bs[kq + 3][mA] = vb.w;
        __syncthreads();
#pragma unroll
        for (int k = 0; k < 16; k++) {
            float a4[4], b4[4];
#pragma unroll
            for (int j = 0; j < 4; j++) { a4[j] = As[k][ty * 4 + j]; b4[j] = Bs[k][tx * 4 + j]; }
#pragma unroll
            for (int i = 0; i < 4; i++)
#pragma unroll
                for (int j = 0; j < 4; j++) c[i][j] = fmaf(a4[i], b4[j], c[i][j]);
        }
    }
#pragma unroll
    for (int i = 0; i < 4; i++) {
        const long m = m0 + ty * 4 + i;
        const float rs = rscale ? rscale[m] : 1.f;
#pragma unroll
        for (int j = 0; j < 4; j++) {
            const int n = n0 + tx * 4 + j;
            float v = c[i][j] * rs;
            if (bias) v += bias[n];
            if (act == 1) v = fmaxf(v, 0.f);
            else if (act == 2) v = tanhf(v);
            C[m * N + n] = v;
        }
    }
}

__global__ void zero_diag_kernel(float* __restrict__ sim)
{
    int i = blockIdx.x * 256 + threadIdx.x;
    if (i < BB) sim[(long)i * BB + i] = 0.f;
}

// ---------------------------------------------------------------------------
// Exact k-th-largest selection: 3-pass radix histogram on monotonic keys.
// ---------------------------------------------------------------------------
__device__ inline unsigned keyOf(float f)
{
    unsigned u = __float_as_uint(f);
    return (u & 0x80000000u) ? ~u : (u | 0x80000000u);
}

__global__ void hist_kernel(const float* __restrict__ sim, unsigned* __restrict__ hist,
                            const unsigned* __restrict__ state, int pass)
{
    __shared__ unsigned h[4096];
    for (int i = threadIdx.x; i < 4096; i += 256) h[i] = 0;
    __syncthreads();
    unsigned pfx1 = 0, pfx2 = 0;
    if (pass == 1) pfx1 = state[0];
    if (pass == 2) pfx2 = state[2];
    const long ntot = (long)BB * BB;
    for (long i = (long)blockIdx.x * 256 + threadIdx.x; i < ntot; i += (long)gridDim.x * 256) {
        unsigned key = keyOf(sim[i]);
        if (pass == 0) atomicAdd(&h[key >> 20], 1u);
        else if (pass == 1) { if ((key >> 20) == pfx1) atomicAdd(&h[(key >> 8) & 0xFFFu], 1u); }
        else               { if ((key >> 8) == pfx2)  atomicAdd(&h[key & 0xFFu], 1u); }
    }
    __syncthreads();
    const int nb = (pass == 2) ? 256 : 4096;
    for (int i = threadIdx.x; i < nb; i += 256)
        if (h[i]) atomicAdd(&hist[i], h[i]);
}

__global__ void scan_hist_kernel(const unsigned* __restrict__ hist, unsigned* __restrict__ state, int pass)
{
    if (threadIdx.x != 0 || blockIdx.x != 0) return;
    long k = (pass == 0) ? NUM_EDGES_ : (long)state[2 * pass - 1];
    const int nb = (pass == 2) ? 256 : 4096;
    long cum = 0; int b = nb - 1;
    for (; b >= 0; b--) { cum += hist[b]; if (cum >= k) break; }
    long kk = k - (cum - hist[b]);
    if (pass == 0) { state[0] = (unsigned)b; state[1] = (unsigned)kk; }
    else if (pass == 1) { state[2] = (state[0] << 12) | (unsigned)b; state[3] = (unsigned)kk; }
    else {
        unsigned key = (state[2] << 8) | (unsigned)b;
        state[4] = key;
        unsigned u = (key & 0x80000000u) ? (key ^ 0x80000000u) : ~key;
        state[5] = u;  // threshold float bits
    }
}

__global__ void degree_kernel(const float* __restrict__ sim, const unsigned* __restrict__ state,
                              float* __restrict__ dinv)
{
    const float thr = __uint_as_float(state[5]);
    const int d = blockIdx.x;
    const float* row = sim + (long)d * BB;
    int cnt = 0;
    for (int s = threadIdx.x; s < BB; s += 256) cnt += (row[s] >= thr) ? 1 : 0;
    for (int o = 32; o; o >>= 1) cnt += __shfl_down(cnt, o, 64);
    __shared__ int sh[4];
    if ((threadIdx.x & 63) == 0) sh[threadIdx.x >> 6] = cnt;
    __syncthreads();
    if (threadIdx.x == 0) {
        int tot = sh[0] + sh[1] + sh[2] + sh[3];
        dinv[d] = rsqrtf((float)(2 * tot + 1));  // each undirected pair counted twice + self loop
    }
}

// ---------------------------------------------------------------------------
// GCN aggregation as dense masked GEMM:
// out[d,c] = relu( dinv[d]*(2*sum_{s: sim[d,s]>=thr} xws[s,c] + xws[d,c]) + b[c] )
// where xws[s,c] = dinv[s]*(x @ W^T)[s,c]   (N fixed = 256)
// ---------------------------------------------------------------------------
__global__ __launch_bounds__(256) void gcn_agg_kernel(
    const float* __restrict__ sim, const float* __restrict__ xws,
    const float* __restrict__ dinv, const float* __restrict__ bias,
    const unsigned* __restrict__ state, float* __restrict__ out)
{
    const float thr = __uint_as_float(state[5]);
    __shared__ float As[16][65];
    __shared__ float Bs[16][65];
    const int tid = threadIdx.x;
    const long m0 = (long)blockIdx.x * 64;
    const int  n0 = blockIdx.y * 64;
    const int ty = tid >> 4, tx = tid & 15;
    const int mA = tid >> 2, kq = (tid & 3) * 4;
    const int kB = tid >> 4, nq = (tid & 15) * 4;
    float c[4][4] = {};
    for (int s0 = 0; s0 < BB; s0 += 16) {
        __syncthreads();
        float4 va = *(const float4*)&sim[(m0 + mA) * (long)BB + s0 + kq];
        As[kq + 0][mA] = (va.x >= thr) ? 1.f : 0.f;
        As[kq + 1][mA] = (va.y >= thr) ? 1.f : 0.f;
        As[kq + 2][mA] = (va.z >= thr) ? 1.f : 0.f;
        As[kq + 3][mA] = (va.w >= thr) ? 1.f : 0.f;
        float4 vb = *(const float4*)&xws[(long)(s0 + kB) * HH + n0 + nq];
        Bs[kB][nq + 0] = vb.x; Bs[kB][nq + 1] = vb.y; Bs[kB][nq + 2] = vb.z; Bs[kB][nq + 3] = vb.w;
        __syncthreads();
#pragma unroll
        for (int k = 0; k < 16; k++) {
            float a4[4], b4[4];
#pragma unroll
            for (int j = 0; j < 4; j++) { a4[j] = As[k][ty * 4 + j]; b4[j] = Bs[k][tx * 4 + j]; }
#pragma unroll
            for (int i = 0; i < 4; i++)
#pragma unroll
                for (int j = 0; j < 4; j++) c[i][j] = fmaf(a4[i], b4[j], c[i][j]);
        }
    }
#pragma unroll
    for (int i = 0; i < 4; i++) {
        const long m = m0 + ty * 4 + i;
        const float dv = dinv[m];
#pragma unroll
        for (int j = 0; j < 4; j++) {
            const int n = n0 + tx * 4 + j;
            float v = dv * (2.f * c[i][j] + xws[m * HH + n]) + bias[n];
            out[m * HH + n] = fmaxf(v, 0.f);
        }
    }
}

// ---------------------------------------------------------------------------
// Small fused kernels
// ---------------------------------------------------------------------------
__global__ void build_gru_feat_kernel(const f16* __restrict__ h2, const float* __restrict__ mf,
                                      float* __restrict__ gf)
{
    long i = (long)blockIdx.x * 256 + threadIdx.x;
    if (i >= (long)BB * 512) return;
    long b = i >> 9; int c = (int)(i & 511);
    gf[i] = (c < 256) ? (float)h2[b * HH + c] : mf[b * HH + (c - 256)];
}

__global__ void build_fused_diff_kernel(const float* __restrict__ g, const float* __restrict__ p,
                                        float* __restrict__ fused, float* __restrict__ diff)
{
    long i = (long)blockIdx.x * 256 + threadIdx.x;
    if (i >= (long)BB * 256) return;
    long b = i >> 8; int c = (int)(i & 255);
    if (c < 128) {
        float gv = g[b * 128 + c], pv = p[b * 128 + c];
        fused[i] = gv;
        diff[b * 128 + c] = gv - pv;
    } else {
        fused[i] = p[b * 128 + (c - 128)];
    }
}

__global__ __launch_bounds__(128) void final_kernel(
    const float* __restrict__ hatt, const float* __restrict__ attn2W, const float* __restrict__ attn2b,
    const float* __restrict__ er, const float* __restrict__ g, const float* __restrict__ p,
    float* __restrict__ pred)
{
    const int b = blockIdx.x;
    __shared__ float w4[4];
    __shared__ float hrow[128];
    const int tid = threadIdx.x;
    hrow[tid] = hatt[(long)b * 128 + tid];
    __syncthreads();
    if (tid < 4) {
        float s = attn2b[tid];
        for (int d = 0; d < 128; d++) s += hrow[d] * attn2W[tid * 128 + d];
        w4[tid] = s;
    }
    __syncthreads();
    if (tid == 0) {
        float mx = fmaxf(fmaxf(w4[0], w4[1]), fmaxf(w4[2], w4[3]));
        float e0 = __expf(w4[0] - mx), e1 = __expf(w4[1] - mx);
        float e2 = __expf(w4[2] - mx), e3 = __expf(w4[3] - mx);
        float inv = 1.f / (e0 + e1 + e2 + e3);
        w4[0] = e0 * inv; w4[1] = e1 * inv; w4[2] = e2 * inv; w4[3] = e3 * inv;
    }
    __syncthreads();
    const long off = (long)b * 128 + tid;
    const long E = (long)BB * DOUT_;
    float base = 0.5f * g[off] + 0.5f * p[off];
    float delta = w4[0] * er[off] + w4[1] * er[off + E] + w4[2] * er[off + 2 * E] + w4[3] * er[off + 3 * E];
    pred[off] = base + 0.1f * delta;
}

// ---------------------------------------------------------------------------
extern "C" void kernel_launch(void* const* d_in, const int* in_sizes, int n_in,
                              void* d_out, int out_size, void* d_ws, size_t ws_size,
                              hipStream_t stream)
{
    const float* input_seq  = (const float*)d_in[0];
    const float* mean_emb   = (const float*)d_in[1];
    const float* prior      = (const float*)d_in[2];
    const float* Wih0       = (const float*)d_in[3];
    const float* Whh0       = (const float*)d_in[4];
    const float* bih0       = (const float*)d_in[5];
    const float* bhh0       = (const float*)d_in[6];
    const float* Wih1       = (const float*)d_in[7];
    const float* Whh1       = (const float*)d_in[8];
    const float* bih1       = (const float*)d_in[9];
    const float* bhh1       = (const float*)d_in[10];
    const float* fc_mean_W  = (const float*)d_in[11];
    const float* fc_mean_b  = (const float*)d_in[12];
    const float* gru_fc_W   = (const float*)d_in[13];
    const float* gru_fc_b   = (const float*)d_in[14];
    const float* gcn1_W     = (const float*)d_in[15];
    const float* gcn1_b     = (const float*)d_in[16];
    const float* gcn2_W     = (const float*)d_in[17];
    const float* gcn2_b     = (const float*)d_in[18];
    const float* prior_fc_W = (const float*)d_in[19];
    const float* prior_fc_b = (const float*)d_in[20];
    const float* expert_W   = (const float*)d_in[21];
    const float* attn1_W    = (const float*)d_in[22];
    const float* attn1_b    = (const float*)d_in[23];
    const float* attn2_W    = (const float*)d_in[24];
    const float* attn2_b    = (const float*)d_in[25];

    float* out_pred = (float*)d_out;
    float* out_g    = out_pred + (long)BB * DOUT_;
    float* out_p    = out_g + (long)BB * DOUT_;

    char* base = (char*)d_ws;
    size_t off = 0;
    auto alloc = [&](size_t bytes) -> char* {
        char* p = base + off;
        off = (off + bytes + 255) & ~(size_t)255;
        return p;
    };
    f16*   wp0    = (f16*)alloc((size_t)1024 * 384 * 2);
    f16*   wp1    = (f16*)alloc((size_t)1024 * 512 * 2);
    float* bias0  = (float*)alloc(1024 * 4);
    float* bias1  = (float*)alloc(1024 * 4);
    f16*   h1b[2]; h1b[0] = (f16*)alloc((size_t)BB * HH * 2); h1b[1] = (f16*)alloc((size_t)BB * HH * 2);
    f16*   h2b[2]; h2b[0] = (f16*)alloc((size_t)BB * HH * 2); h2b[1] = (f16*)alloc((size_t)BB * HH * 2);
    float* sim    = (float*)alloc((size_t)BB * BB * 4);
    unsigned* hist  = (unsigned*)alloc(4096 * 4);
    unsigned* state = (unsigned*)alloc(256);
    float* dinv   = (float*)alloc(BB * 4);
    float* mf     = (float*)alloc((size_t)BB * HH * 4);
    float* gf     = (float*)alloc((size_t)BB * 2 * HH * 4);
    float* xws1   = (float*)alloc((size_t)BB * HH * 4);
    float* ph1    = (float*)alloc((size_t)BB * HH * 4);
    float* xws2   = (float*)alloc((size_t)BB * HH * 4);
    float* ph2    = (float*)alloc((size_t)BB * HH * 4);
    float* diffb  = (float*)alloc((size_t)BB * DOUT_ * 4);
    float* fusedb = (float*)alloc((size_t)BB * 2 * DOUT_ * 4);
    float* hatt   = (float*)alloc((size_t)BB * DOUT_ * 4);
    float* er     = (float*)alloc((size_t)NEXP_ * BB * DOUT_ * 4);
    if (off > ws_size) return;  // workspace insufficient — bail (bench will flag)

    // --- weight packing + state init ---
    pack_weights_kernel<<<1536, 256, 0, stream>>>(Wih0, Whh0, wp0, DSEQ_);
    pack_weights_kernel<<<2048, 256, 0, stream>>>(Wih1, Whh1, wp1, HH);
    pack_bias_kernel<<<4, 256, 0, stream>>>(bih0, bhh0, bias0);
    pack_bias_kernel<<<4, 256, 0, stream>>>(bih1, bhh1, bias1);
    hipMemsetAsync(h1b[0], 0, (size_t)BB * HH * 2, stream);
    hipMemsetAsync(h1b[1], 0, (size_t)BB * HH * 2, stream);
    hipMemsetAsync(h2b[0], 0, (size_t)BB * HH * 2, stream);
    hipMemsetAsync(h2b[1], 0, (size_t)BB * HH * 2, stream);

    // --- GRU: 129 pipelined supersteps (layer0 at tau, layer1 at tau-1) ---
    for (int tau = 0; tau <= TT; tau++) {
        gru_superstep<<<dim3(32, 8, 2), 256, 0, stream>>>(
            wp0, bias0, input_seq, h1b[tau & 1], h1b[(tau + 1) & 1], tau,
            wp1, bias1, h1b[tau & 1], h2b[tau & 1], h2b[(tau + 1) & 1], tau - 1);
    }
    const f16* h2fin = h2b[(TT + 1) & 1];

    // --- GRU head ---
    gemm_bt_kernel<<<dim3(64, 4), 256, 0, stream>>>(mean_emb, fc_mean_W, mf, BB, HH, 256, fc_mean_b, nullptr, 1);
    build_gru_feat_kernel<<<(BB * 512) / 256, 256, 0, stream>>>(h2fin, mf, gf);
    gemm_bt_kernel<<<dim3(64, 2), 256, 0, stream>>>(gf, gru_fc_W, out_g, BB, DOUT_, 512, gru_fc_b, nullptr, 0);

    // --- similarity + exact top-k threshold ---
    gemm_bt_kernel<<<dim3(64, 64), 256, 0, stream>>>(prior, prior, sim, BB, BB, 256, nullptr, nullptr, 0);
    zero_diag_kernel<<<16, 256, 0, stream>>>(sim);
    for (int pass = 0; pass < 3; pass++) {
        hipMemsetAsync(hist, 0, 4096 * 4, stream);
        hist_kernel<<<1024, 256, 0, stream>>>(sim, hist, state, pass);
        scan_hist_kernel<<<1, 64, 0, stream>>>(hist, state, pass);
    }
    degree_kernel<<<BB, 256, 0, stream>>>(sim, state, dinv);

    // --- GCN (dense masked aggregation) ---
    gemm_bt_kernel<<<dim3(64, 4), 256, 0, stream>>>(prior, gcn1_W, xws1, BB, HH, 256, nullptr, dinv, 0);
    gcn_agg_kernel<<<dim3(64, 4), 256, 0, stream>>>(sim, xws1, dinv, gcn1_b, state, ph1);
    gemm_bt_kernel<<<dim3(64, 4), 256, 0, stream>>>(ph1, gcn2_W, xws2, BB, HH, 256, nullptr, dinv, 0);
    gcn_agg_kernel<<<dim3(64, 4), 256, 0, stream>>>(sim, xws2, dinv, gcn2_b, state, ph2);
    gemm_bt_kernel<<<dim3(64, 2), 256, 0, stream>>>(ph2, prior_fc_W, out_p, BB, DOUT_, 256, prior_fc_b, nullptr, 0);

    // --- fusion: experts + attention ---
    build_fused_diff_kernel<<<(BB * 256) / 256, 256, 0, stream>>>(out_g, out_p, fusedb, diffb);
    for (int e = 0; e < NEXP_; e++)
        gemm_bt_kernel<<<dim3(64, 2), 256, 0, stream>>>(diffb, expert_W + (long)e * DOUT_ * DOUT_,
                                                        er + (long)e * BB * DOUT_, BB, DOUT_, DOUT_,
                                                        nullptr, nullptr, 0);
    gemm_bt_kernel<<<dim3(64, 2), 256, 0, stream>>>(fusedb, attn1_W, hatt, BB, DOUT_, 256, attn1_b, nullptr, 2);
    final_kernel<<<BB, 128, 0, stream>>>(hatt, attn2_W, attn2_b, er, out_g, out_p, out_pred);
}

// Round 2
// 5198.269 us; speedup vs baseline: 1.1941x; 1.1941x over previous
//
#include <hip/hip_runtime.h>
#include <hip/hip_bf16.h>

// Problem constants
#define BB    4096
#define TT    128
#define DSEQ_ 128
#define HH    256
#define DOUT_ 128
#define NEXP_ 4
static const long NUM_EDGES_ = 838860;  // int(4096*4096*0.05)

typedef _Float16 f16;
typedef _Float16 f16x8 __attribute__((ext_vector_type(8)));
typedef float    f32x4 __attribute__((ext_vector_type(4)));

// async global->LDS, 16B per lane, wave-uniform LDS base + lane*16
#define GLL(gp, lp) __builtin_amdgcn_global_load_lds( \
    (const __attribute__((address_space(1))) void*)(gp), \
    (__attribute__((address_space(3))) void*)(lp), 16, 0, 0)

// ---------------------------------------------------------------------------
// Weight packing: Wp[n][k], n = 4*u + g  (g: 0=r, 1=z, 2=i_n, 3=h_n)
// ---------------------------------------------------------------------------
__global__ void pack_weights_kernel(const float* __restrict__ Wih,
                                    const float* __restrict__ Whh,
                                    f16* __restrict__ Wp, int Din)
{
    const int K = Din + HH;
    const int total = 1024 * K;
    for (int idx = blockIdx.x * 256 + threadIdx.x; idx < total; idx += gridDim.x * 256) {
        int n = idx / K, k = idx % K;
        int u = n >> 2, g = n & 3;
        float v = 0.f;
        if (k < Din) {
            if (g == 0)      v = Wih[(long)u * Din + k];
            else if (g == 1) v = Wih[(long)(256 + u) * Din + k];
            else if (g == 2) v = Wih[(long)(512 + u) * Din + k];
        } else {
            int kh = k - Din;
            if (g == 0)      v = Whh[(long)u * HH + kh];
            else if (g == 1) v = Whh[(long)(256 + u) * HH + kh];
            else if (g == 3) v = Whh[(long)(512 + u) * HH + kh];
        }
        Wp[idx] = (f16)v;
    }
}

__global__ void pack_bias_kernel(const float* __restrict__ bih,
                                 const float* __restrict__ bhh,
                                 float* __restrict__ bias)
{
    int n = blockIdx.x * 256 + threadIdx.x;
    if (n >= 1024) return;
    int u = n >> 2, g = n & 3;
    float v;
    if (g == 0)      v = bih[u] + bhh[u];
    else if (g == 1) v = bih[256 + u] + bhh[256 + u];
    else if (g == 2) v = bih[512 + u];
    else             v = bhh[512 + u];
    bias[n] = v;
}

// ---------------------------------------------------------------------------
// Shared MFMA K-loop core: 128x128 tile, BK=32 f16, async staging both operands.
// LDS layout: As/Bs[row*32 + col] f16 (64B rows, no padding — required by GLL).
// ---------------------------------------------------------------------------
__device__ __forceinline__ void mm_async(
    f32x4 (&acc)[4][4], f16* __restrict__ As, f16* __restrict__ Bs,
    const f16* __restrict__ Ag, long lda, const f16* __restrict__ Bg, long ldb,
    int kChunks, int wave, int lane)
{
    const int r0 = wave * 32 + (lane >> 2);
    const int ce = (lane & 3) * 8;
    const int wm = wave >> 1, wn = wave & 1;
    const int quad = lane >> 4, l15 = lane & 15;
    const f16* ag0 = Ag + (long)r0 * lda + ce;
    const f16* ag1 = ag0 + 16 * lda;
    const f16* bg0 = Bg + (long)r0 * ldb + ce;
    const f16* bg1 = bg0 + 16 * ldb;
    f16* asw = As + wave * 1024;
    f16* bsw = Bs + wave * 1024;
    for (int kc = 0; kc < kChunks; kc++) {
        __syncthreads();
        GLL(ag0, asw); GLL(ag1, asw + 512);
        GLL(bg0, bsw); GLL(bg1, bsw + 512);
        ag0 += 32; ag1 += 32; bg0 += 32; bg1 += 32;
        __syncthreads();
        f16x8 af[4], bf[4];
#pragma unroll
        for (int i = 0; i < 4; i++) {
            af[i] = *(const f16x8*)&As[(wm * 64 + i * 16 + l15) * 32 + quad * 8];
            bf[i] = *(const f16x8*)&Bs[(wn * 64 + i * 16 + l15) * 32 + quad * 8];
        }
#pragma unroll
        for (int mi = 0; mi < 4; mi++)
#pragma unroll
            for (int ni = 0; ni < 4; ni++)
                acc[mi][ni] = __builtin_amdgcn_mfma_f32_16x16x32_f16(af[mi], bf[ni], acc[mi][ni], 0, 0, 0);
    }
}

// ---------------------------------------------------------------------------
// GRU superstep: z==0 -> layer0 at t0, z==1 -> layer1 at t1.
// ---------------------------------------------------------------------------
__global__ __launch_bounds__(256) void gru_superstep(
    const f16* __restrict__ Wp0, const float* __restrict__ bias0,
    const float* __restrict__ xseq,
    const f16* __restrict__ h1_in, f16* __restrict__ h1_out, int t0,
    const f16* __restrict__ Wp1, const float* __restrict__ bias1,
    const f16* __restrict__ h1_x,
    const f16* __restrict__ h2_in, f16* __restrict__ h2_out, int t1)
{
    const int layer = blockIdx.z;
    if (layer == 0 && t0 >= TT) return;
    if (layer == 1 && t1 < 0) return;

    __shared__ f16 As[4096];
    __shared__ f16 Bs[4096];
    const int tid = threadIdx.x;
    const int wave = tid >> 6, lane = tid & 63;
    const int wm = wave >> 1, wn = wave & 1;
    const int quad = lane >> 4, l15 = lane & 15;
    const long m0 = (long)blockIdx.x * 128;
    const int  n0 = blockIdx.y * 128;

    f32x4 acc[4][4];
#pragma unroll
    for (int i = 0; i < 4; i++)
#pragma unroll
        for (int j = 0; j < 4; j++) acc[i][j] = (f32x4){0.f, 0.f, 0.f, 0.f};

    const f16* hprev; f16* hout; const float* bias;
    if (layer == 0) {
        hprev = h1_in; hout = h1_out; bias = bias0;
        // x phase: 4 chunks, A manual (fp32 -> f16 convert), B async
        const int arow = tid >> 1, ac0 = (tid & 1) * 16;
        const float* ap = xseq + (m0 + arow) * ((long)TT * DSEQ_) + (long)t0 * DSEQ_ + ac0;
        const int r0 = wave * 32 + (lane >> 2);
        const int ce = (lane & 3) * 8;
        const f16* bg0 = Wp0 + (long)(n0 + r0) * 384 + ce;
        const f16* bg1 = bg0 + 16 * 384;
        f16* bsw = Bs + wave * 1024;
        for (int kc = 0; kc < 4; kc++) {
            float4 v0 = *(const float4*)(ap + 0);
            float4 v1 = *(const float4*)(ap + 4);
            float4 v2 = *(const float4*)(ap + 8);
            float4 v3 = *(const float4*)(ap + 12);
            ap += 32;
            __syncthreads();
            f16x8 w0, w1;
            w0[0] = (f16)v0.x; w0[1] = (f16)v0.y; w0[2] = (f16)v0.z; w0[3] = (f16)v0.w;
            w0[4] = (f16)v1.x; w0[5] = (f16)v1.y; w0[6] = (f16)v1.z; w0[7] = (f16)v1.w;
            w1[0] = (f16)v2.x; w1[1] = (f16)v2.y; w1[2] = (f16)v2.z; w1[3] = (f16)v2.w;
            w1[4] = (f16)v3.x; w1[5] = (f16)v3.y; w1[6] = (f16)v3.z; w1[7] = (f16)v3.w;
            *(f16x8*)&As[arow * 32 + ac0]     = w0;
            *(f16x8*)&As[arow * 32 + ac0 + 8] = w1;
            GLL(bg0, bsw); GLL(bg1, bsw + 512);
            bg0 += 32; bg1 += 32;
            __syncthreads();
            f16x8 af[4], bf[4];
#pragma unroll
            for (int i = 0; i < 4; i++) {
                af[i] = *(const f16x8*)&As[(wm * 64 + i * 16 + l15) * 32 + quad * 8];
                bf[i] = *(const f16x8*)&Bs[(wn * 64 + i * 16 + l15) * 32 + quad * 8];
            }
#pragma unroll
            for (int mi = 0; mi < 4; mi++)
#pragma unroll
                for (int ni = 0; ni < 4; ni++)
                    acc[mi][ni] = __builtin_amdgcn_mfma_f32_16x16x32_f16(af[mi], bf[ni], acc[mi][ni], 0, 0, 0);
        }
        // h phase: 8 chunks, all async
        mm_async(acc, As, Bs, h1_in + m0 * HH, HH, Wp0 + (long)n0 * 384 + 128, 384, 8, wave, lane);
    } else {
        hprev = h2_in; hout = h2_out; bias = bias1;
        mm_async(acc, As, Bs, h1_x + m0 * HH, HH, Wp1 + (long)n0 * 512, 512, 8, wave, lane);
        mm_async(acc, As, Bs, h2_in + m0 * HH, HH, Wp1 + (long)n0 * 512 + 256, 512, 8, wave, lane);
    }

    // Fused gate epilogue. C layout: row = quad*4+reg, col = l15.
    const long mbase = m0 + wm * 64;
    const int  nbase = n0 + wn * 64;
#pragma unroll
    for (int mi = 0; mi < 4; mi++) {
#pragma unroll
        for (int ni = 0; ni < 4; ni++) {
            const int ncol = nbase + ni * 16 + l15;
            const float bn = bias[ncol];
#pragma unroll
            for (int reg = 0; reg < 4; reg++) {
                float v = acc[mi][ni][reg] + bn;
                const int gb = lane & ~3;
                float g0 = __shfl(v, gb + 0, 64);
                float g1 = __shfl(v, gb + 1, 64);
                float g2 = __shfl(v, gb + 2, 64);
                float g3 = __shfl(v, gb + 3, 64);
                if ((lane & 3) == 0) {
                    const long mrow = mbase + mi * 16 + quad * 4 + reg;
                    const int u = ncol >> 2;
                    float hp = (float)hprev[mrow * HH + u];
                    float r = 1.f / (1.f + __expf(-g0));
                    float z = 1.f / (1.f + __expf(-g1));
                    float ng = 1.f - 2.f / (__expf(2.f * (g2 + r * g3)) + 1.f);  // tanh
                    float hn = (1.f - z) * ng + z * hp;
                    hout[mrow * HH + u] = (f16)hn;
                }
            }
        }
    }
}

// ---------------------------------------------------------------------------
// sim = prior @ prior^T via split-f16 MFMA (K=768: hi|hi|lo vs hi|lo|hi).
// ---------------------------------------------------------------------------
__global__ void sim_pack_kernel(const float* __restrict__ prior,
                                f16* __restrict__ pA, f16* __restrict__ pB)
{
    int i = blockIdx.x * 256 + threadIdx.x;
    if (i >= BB * 256) return;
    int b = i >> 8, k = i & 255;
    float v = prior[i];
    f16 hi = (f16)v;
    f16 lo = (f16)(v - (float)hi);
    long r = (long)b * 768;
    pA[r + k] = hi; pA[r + 256 + k] = hi; pA[r + 512 + k] = lo;
    pB[r + k] = hi; pB[r + 256 + k] = lo; pB[r + 512 + k] = hi;
}

__global__ __launch_bounds__(256) void sim_mm_kernel(
    const f16* __restrict__ pA, const f16* __restrict__ pB, float* __restrict__ sim)
{
    __shared__ f16 As[4096];
    __shared__ f16 Bs[4096];
    const int tid = threadIdx.x;
    const int wave = tid >> 6, lane = tid & 63;
    const int wm = wave >> 1, wn = wave & 1;
    const int quad = lane >> 4, l15 = lane & 15;
    const long m0 = (long)blockIdx.x * 128;
    const int  n0 = blockIdx.y * 128;
    f32x4 acc[4][4];
#pragma unroll
    for (int i = 0; i < 4; i++)
#pragma unroll
        for (int j = 0; j < 4; j++) acc[i][j] = (f32x4){0.f, 0.f, 0.f, 0.f};
    mm_async(acc, As, Bs, pA + m0 * 768, 768, pB + (long)n0 * 768, 768, 24, wave, lane);
    const long mbase = m0 + wm * 64;
    const int  nbase = n0 + wn * 64;
#pragma unroll
    for (int mi = 0; mi < 4; mi++)
#pragma unroll
        for (int ni = 0; ni < 4; ni++)
#pragma unroll
            for (int reg = 0; reg < 4; reg++) {
                long row = mbase + mi * 16 + quad * 4 + reg;
                int col = nbase + ni * 16 + l15;
                float v = acc[mi][ni][reg];
                if (row == (long)col) v = 0.f;
                sim[row * BB + col] = v;
            }
}

// ---------------------------------------------------------------------------
// Exact k-th-largest selection: 3-pass radix histogram on monotonic keys.
// ---------------------------------------------------------------------------
__device__ inline unsigned keyOf(float f)
{
    unsigned u = __float_as_uint(f);
    return (u & 0x80000000u) ? ~u : (u | 0x80000000u);
}

__global__ void hist_kernel(const float* __restrict__ sim, unsigned* __restrict__ hist,
                            const unsigned* __restrict__ state, int pass)
{
    __shared__ unsigned h[4096];
    for (int i = threadIdx.x; i < 4096; i += 256) h[i] = 0;
    __syncthreads();
    unsigned pfx1 = 0, pfx2 = 0;
    if (pass == 1) pfx1 = state[0];
    if (pass == 2) pfx2 = state[2];
    const long ntot = (long)BB * BB;
    for (long i = (long)blockIdx.x * 256 + threadIdx.x; i < ntot; i += (long)gridDim.x * 256) {
        unsigned key = keyOf(sim[i]);
        if (pass == 0) atomicAdd(&h[key >> 20], 1u);
        else if (pass == 1) { if ((key >> 20) == pfx1) atomicAdd(&h[(key >> 8) & 0xFFFu], 1u); }
        else               { if ((key >> 8) == pfx2)  atomicAdd(&h[key & 0xFFu], 1u); }
    }
    __syncthreads();
    const int nb = (pass == 2) ? 256 : 4096;
    for (int i = threadIdx.x; i < nb; i += 256)
        if (h[i]) atomicAdd(&hist[i], h[i]);
}

__global__ void scan_hist_kernel(const unsigned* __restrict__ hist,
                                 unsigned* __restrict__ state, int pass)
{
    __shared__ unsigned hl[4096];
    const int nb = (pass == 2) ? 256 : 4096;
    for (int i = threadIdx.x; i < nb; i += 256) hl[i] = hist[i];
    __syncthreads();
    if (threadIdx.x != 0 || blockIdx.x != 0) return;
    long k = (pass == 0) ? NUM_EDGES_ : (long)state[2 * pass - 1];
    long cum = 0; int b = nb - 1;
    for (; b >= 0; b--) { cum += hl[b]; if (cum >= k) break; }
    long kk = k - (cum - hl[b]);
    if (pass == 0) { state[0] = (unsigned)b; state[1] = (unsigned)kk; }
    else if (pass == 1) { state[2] = (state[0] << 12) | (unsigned)b; state[3] = (unsigned)kk; }
    else {
        unsigned key = (state[2] << 8) | (unsigned)b;
        state[4] = key;
        unsigned u = (key & 0x80000000u) ? (key ^ 0x80000000u) : ~key;
        state[5] = u;  // threshold float bits
    }
}

__global__ void degree_kernel(const float* __restrict__ sim, const unsigned* __restrict__ state,
                              float* __restrict__ dinv)
{
    const float thr = __uint_as_float(state[5]);
    const int d = blockIdx.x;
    const float* row = sim + (long)d * BB;
    int cnt = 0;
    for (int s = threadIdx.x; s < BB; s += 256) cnt += (row[s] >= thr) ? 1 : 0;
    for (int o = 32; o; o >>= 1) cnt += __shfl_down(cnt, o, 64);
    __shared__ int sh[4];
    if ((threadIdx.x & 63) == 0) sh[threadIdx.x >> 6] = cnt;
    __syncthreads();
    if (threadIdx.x == 0) {
        int tot = sh[0] + sh[1] + sh[2] + sh[3];
        dinv[d] = rsqrtf((float)(2 * tot + 1));
    }
}

// ---------------------------------------------------------------------------
// GCN aggregation: MFMA masked GEMM, split-K=4.
// A = (sim >= thr) built on the fly (f16 0/1), B = xws^T (f16), partials fp32.
// ---------------------------------------------------------------------------
__global__ void txp_kernel(const float* __restrict__ xws, f16* __restrict__ bT)
{
    int i = blockIdx.x * 256 + threadIdx.x;
    if (i >= BB * 256) return;
    int n = i >> 12, m = i & 4095;
    bT[(long)n * BB + m] = (f16)xws[(long)m * 256 + n];
}

__global__ __launch_bounds__(256) void gcn_mm_kernel(
    const float* __restrict__ sim, const f16* __restrict__ bT,
    const unsigned* __restrict__ state, float* __restrict__ ps)
{
    const float thr = __uint_as_float(state[5]);
    __shared__ f16 As[4096];
    __shared__ f16 Bs[4096];
    const int tid = threadIdx.x;
    const int wave = tid >> 6, lane = tid & 63;
    const int wm = wave >> 1, wn = wave & 1;
    const int quad = lane >> 4, l15 = lane & 15;
    const long m0 = (long)blockIdx.x * 128;
    const int  n0 = blockIdx.y * 128;
    const long kbase = (long)blockIdx.z * 1024;
    f32x4 acc[4][4];
#pragma unroll
    for (int i = 0; i < 4; i++)
#pragma unroll
        for (int j = 0; j < 4; j++) acc[i][j] = (f32x4){0.f, 0.f, 0.f, 0.f};

    const int arow = tid >> 1, ac0 = (tid & 1) * 16;
    const float* ap = sim + (m0 + arow) * (long)BB + kbase + ac0;
    const int r0 = wave * 32 + (lane >> 2);
    const int ce = (lane & 3) * 8;
    const f16* bg0 = bT + (long)(n0 + r0) * BB + kbase + ce;
    const f16* bg1 = bg0 + 16 * BB;
    f16* bsw = Bs + wave * 1024;
    const f16 one = (f16)1.f, zero = (f16)0.f;
    for (int kc = 0; kc < 32; kc++) {
        float4 v0 = *(const float4*)(ap + 0);
        float4 v1 = *(const float4*)(ap + 4);
        float4 v2 = *(const float4*)(ap + 8);
        float4 v3 = *(const float4*)(ap + 12);
        ap += 32;
        __syncthreads();
        f16x8 w0, w1;
        w0[0] = v0.x >= thr ? one : zero; w0[1] = v0.y >= thr ? one : zero;
        w0[2] = v0.z >= thr ? one : zero; w0[3] = v0.w >= thr ? one : zero;
        w0[4] = v1.x >= thr ? one : zero; w0[5] = v1.y >= thr ? one : zero;
        w0[6] = v1.z >= thr ? one : zero; w0[7] = v1.w >= thr ? one : zero;
        w1[0] = v2.x >= thr ? one : zero; w1[1] = v2.y >= thr ? one : zero;
        w1[2] = v2.z >= thr ? one : zero; w1[3] = v2.w >= thr ? one : zero;
        w1[4] = v3.x >= thr ? one : zero; w1[5] = v3.y >= thr ? one : zero;
        w1[6] = v3.z >= thr ? one : zero; w1[7] = v3.w >= thr ? one : zero;
        *(f16x8*)&As[arow * 32 + ac0]     = w0;
        *(f16x8*)&As[arow * 32 + ac0 + 8] = w1;
        GLL(bg0, bsw); GLL(bg1, bsw + 512);
        bg0 += 32; bg1 += 32;
        __syncthreads();
        f16x8 af[4], bf[4];
#pragma unroll
        for (int i = 0; i < 4; i++) {
            af[i] = *(const f16x8*)&As[(wm * 64 + i * 16 + l15) * 32 + quad * 8];
            bf[i] = *(const f16x8*)&Bs[(wn * 64 + i * 16 + l15) * 32 + quad * 8];
        }
#pragma unroll
        for (int mi = 0; mi < 4; mi++)
#pragma unroll
            for (int ni = 0; ni < 4; ni++)
                acc[mi][ni] = __builtin_amdgcn_mfma_f32_16x16x32_f16(af[mi], bf[ni], acc[mi][ni], 0, 0, 0);
    }
    const long mbase = m0 + wm * 64;
    const int  nbase = n0 + wn * 64;
    float* pbase = ps + (long)blockIdx.z * BB * 256;
#pragma unroll
    for (int mi = 0; mi < 4; mi++)
#pragma unroll
        for (int ni = 0; ni < 4; ni++)
#pragma unroll
            for (int reg = 0; reg < 4; reg++) {
                long row = mbase + mi * 16 + quad * 4 + reg;
                int col = nbase + ni * 16 + l15;
                pbase[row * 256 + col] = acc[mi][ni][reg];
            }
}

__global__ void gcn_combine_kernel(const float* __restrict__ ps, const float* __restrict__ xws,
                                   const float* __restrict__ dinv, const float* __restrict__ b,
                                   float* __restrict__ out)
{
    const long S = (long)BB * 256;
    long i = (long)blockIdx.x * 256 + threadIdx.x;
    if (i >= S) return;
    float s = ps[i] + ps[i + S] + ps[i + 2 * S] + ps[i + 3 * S];
    long m = i >> 8; int n = (int)(i & 255);
    out[i] = fmaxf(dinv[m] * (2.f * s + xws[i]) + b[n], 0.f);
}

// ---------------------------------------------------------------------------
// Generic fp32 GEMM (small shapes): C = act(rscale[m]*A@B^T + bias)
// ---------------------------------------------------------------------------
__global__ __launch_bounds__(256) void gemm_bt_kernel(
    const float* __restrict__ A, const float* __restrict__ Bm, float* __restrict__ C,
    int M, int N, int K, const float* __restrict__ bias,
    const float* __restrict__ rscale, int act)
{
    __shared__ float As[16][65];
    __shared__ float Bs[16][65];
    const int tid = threadIdx.x;
    const long m0 = (long)blockIdx.x * 64;
    const int  n0 = blockIdx.y * 64;
    const int ty = tid >> 4, tx = tid & 15;
    const int mA = tid >> 2, kq = (tid & 3) * 4;
    float c[4][4] = {};
    for (int k0 = 0; k0 < K; k0 += 16) {
        __syncthreads();
        float4 va = *(const float4*)&A[(m0 + mA) * K + k0 + kq];
        As[kq + 0][mA] = va.x; As[kq + 1][mA] = va.y; As[kq + 2][mA] = va.z; As[kq + 3][mA] = va.w;
        float4 vb = *(const float4*)&Bm[(long)(n0 + mA) * K + k0 + kq];
        Bs[kq + 0][mA] = vb.x; Bs[kq + 1][mA] = vb.y; Bs[kq + 2][mA] = vb.z; Bs[kq + 3][mA] = vb.w;
        __syncthreads();
#pragma unroll
        for (int k = 0; k < 16; k++) {
            float a4[4], b4[4];
#pragma unroll
            for (int j = 0; j < 4; j++) { a4[j] = As[k][ty * 4 + j]; b4[j] = Bs[k][tx * 4 + j]; }
#pragma unroll
            for (int i = 0; i < 4; i++)
#pragma unroll
                for (int j = 0; j < 4; j++) c[i][j] = fmaf(a4[i], b4[j], c[i][j]);
        }
    }
#pragma unroll
    for (int i = 0; i < 4; i++) {
        const long m = m0 + ty * 4 + i;
        const float rs = rscale ? rscale[m] : 1.f;
#pragma unroll
        for (int j = 0; j < 4; j++) {
            const int n = n0 + tx * 4 + j;
            float v = c[i][j] * rs;
            if (bias) v += bias[n];
            if (act == 1) v = fmaxf(v, 0.f);
            else if (act == 2) v = tanhf(v);
            C[m * N + n] = v;
        }
    }
}

// ---------------------------------------------------------------------------
// Small fused kernels
// ---------------------------------------------------------------------------
__global__ void build_gru_feat_kernel(const f16* __restrict__ h2, const float* __restrict__ mf,
                                      float* __restrict__ gf)
{
    long i = (long)blockIdx.x * 256 + threadIdx.x;
    if (i >= (long)BB * 512) return;
    long b = i >> 9; int c = (int)(i & 511);
    gf[i] = (c < 256) ? (float)h2[b * HH + c] : mf[b * HH + (c - 256)];
}

__global__ void build_fused_diff_kernel(const float* __restrict__ g, const float* __restrict__ p,
                                        float* __restrict__ fused, float* __restrict__ diff)
{
    long i = (long)blockIdx.x * 256 + threadIdx.x;
    if (i >= (long)BB * 256) return;
    long b = i >> 8; int c = (int)(i & 255);
    if (c < 128) {
        float gv = g[b * 128 + c], pv = p[b * 128 + c];
        fused[i] = gv;
        diff[b * 128 + c] = gv - pv;
    } else {
        fused[i] = p[b * 128 + (c - 128)];
    }
}

__global__ __launch_bounds__(128) void final_kernel(
    const float* __restrict__ hatt, const float* __restrict__ attn2W, const float* __restrict__ attn2b,
    const float* __restrict__ er, const float* __restrict__ g, const float* __restrict__ p,
    float* __restrict__ pred)
{
    const int b = blockIdx.x;
    __shared__ float w4[4];
    __shared__ float hrow[128];
    const int tid = threadIdx.x;
    hrow[tid] = hatt[(long)b * 128 + tid];
    __syncthreads();
    if (tid < 4) {
        float s = attn2b[tid];
        for (int d = 0; d < 128; d++) s += hrow[d] * attn2W[tid * 128 + d];
        w4[tid] = s;
    }
    __syncthreads();
    if (tid == 0) {
        float mx = fmaxf(fmaxf(w4[0], w4[1]), fmaxf(w4[2], w4[3]));
        float e0 = __expf(w4[0] - mx), e1 = __expf(w4[1] - mx);
        float e2 = __expf(w4[2] - mx), e3 = __expf(w4[3] - mx);
        float inv = 1.f / (e0 + e1 + e2 + e3);
        w4[0] = e0 * inv; w4[1] = e1 * inv; w4[2] = e2 * inv; w4[3] = e3 * inv;
    }
    __syncthreads();
    const long off = (long)b * 128 + tid;
    const long E = (long)BB * DOUT_;
    float base = 0.5f * g[off] + 0.5f * p[off];
    float delta = w4[0] * er[off] + w4[1] * er[off + E] + w4[2] * er[off + 2 * E] + w4[3] * er[off + 3 * E];
    pred[off] = base + 0.1f * delta;
}

// ---------------------------------------------------------------------------
extern "C" void kernel_launch(void* const* d_in, const int* in_sizes, int n_in,
                              void* d_out, int out_size, void* d_ws, size_t ws_size,
                              hipStream_t stream)
{
    const float* input_seq  = (const float*)d_in[0];
    const float* mean_emb   = (const float*)d_in[1];
    const float* prior      = (const float*)d_in[2];
    const float* Wih0       = (const float*)d_in[3];
    const float* Whh0       = (const float*)d_in[4];
    const float* bih0       = (const float*)d_in[5];
    const float* bhh0       = (const float*)d_in[6];
    const float* Wih1       = (const float*)d_in[7];
    const float* Whh1       = (const float*)d_in[8];
    const float* bih1       = (const float*)d_in[9];
    const float* bhh1       = (const float*)d_in[10];
    const float* fc_mean_W  = (const float*)d_in[11];
    const float* fc_mean_b  = (const float*)d_in[12];
    const float* gru_fc_W   = (const float*)d_in[13];
    const float* gru_fc_b   = (const float*)d_in[14];
    const float* gcn1_W     = (const float*)d_in[15];
    const float* gcn1_b     = (const float*)d_in[16];
    const float* gcn2_W     = (const float*)d_in[17];
    const float* gcn2_b     = (const float*)d_in[18];
    const float* prior_fc_W = (const float*)d_in[19];
    const float* prior_fc_b = (const float*)d_in[20];
    const float* expert_W   = (const float*)d_in[21];
    const float* attn1_W    = (const float*)d_in[22];
    const float* attn1_b    = (const float*)d_in[23];
    const float* attn2_W    = (const float*)d_in[24];
    const float* attn2_b    = (const float*)d_in[25];

    float* out_pred = (float*)d_out;
    float* out_g    = out_pred + (long)BB * DOUT_;
    float* out_p    = out_g + (long)BB * DOUT_;

    const size_t MB = 1u << 20;
    char* base = (char*)d_ws;
    size_t off = 0;
    auto alloc = [&](size_t bytes) -> char* {
        char* p = base + off;
        off = (off + bytes + 255) & ~(size_t)255;
        return p;
    };
    f16*   wp0    = (f16*)alloc((size_t)1024 * 384 * 2);
    f16*   wp1    = (f16*)alloc((size_t)1024 * 512 * 2);
    float* bias0  = (float*)alloc(1024 * 4);
    float* bias1  = (float*)alloc(1024 * 4);
    f16*   h1b[2]; h1b[0] = (f16*)alloc((size_t)BB * HH * 2); h1b[1] = (f16*)alloc((size_t)BB * HH * 2);
    f16*   h2b[2]; h2b[0] = (f16*)alloc((size_t)BB * HH * 2); h2b[1] = (f16*)alloc((size_t)BB * HH * 2);
    float* sim    = (float*)alloc((size_t)BB * BB * 4);       // 67 MB
    unsigned* hist  = (unsigned*)alloc(4096 * 4);
    unsigned* state = (unsigned*)alloc(256);
    float* dinv   = (float*)alloc(BB * 4);
    float* xws1   = (float*)alloc((size_t)BB * HH * 4);
    float* ph1    = (float*)alloc((size_t)BB * HH * 4);
    float* xws2   = (float*)alloc((size_t)BB * HH * 4);
    float* ph2    = (float*)alloc((size_t)BB * HH * 4);
    f16*   xwsT16 = (f16*)alloc((size_t)256 * BB * 2);
    char*  region = alloc(20 * MB);                            // phase-shared
    if (off > ws_size) return;

    // region aliases (phases are stream-ordered, lifetimes disjoint)
    float* mf     = (float*)(region);                 // head phase
    float* gf     = (float*)(region + 5 * MB);
    f16*   packA  = (f16*)(region);                   // sim phase
    f16*   packB  = (f16*)(region + 7 * MB);
    float* ps     = (float*)(region);                 // gcn phase (16.78 MB)
    float* diffb  = (float*)(region);                 // fusion phase
    float* fusedb = (float*)(region + 3 * MB);
    float* hatt   = (float*)(region + 8 * MB);
    float* er     = (float*)(region + 11 * MB);

    // --- weight packing + state init ---
    pack_weights_kernel<<<1536, 256, 0, stream>>>(Wih0, Whh0, wp0, DSEQ_);
    pack_weights_kernel<<<2048, 256, 0, stream>>>(Wih1, Whh1, wp1, HH);
    pack_bias_kernel<<<4, 256, 0, stream>>>(bih0, bhh0, bias0);
    pack_bias_kernel<<<4, 256, 0, stream>>>(bih1, bhh1, bias1);
    hipMemsetAsync(h1b[0], 0, (size_t)BB * HH * 2, stream);
    hipMemsetAsync(h1b[1], 0, (size_t)BB * HH * 2, stream);
    hipMemsetAsync(h2b[0], 0, (size_t)BB * HH * 2, stream);
    hipMemsetAsync(h2b[1], 0, (size_t)BB * HH * 2, stream);

    // --- GRU: 129 pipelined supersteps ---
    for (int tau = 0; tau <= TT; tau++) {
        gru_superstep<<<dim3(32, 8, 2), 256, 0, stream>>>(
            wp0, bias0, input_seq, h1b[tau & 1], h1b[(tau + 1) & 1], tau,
            wp1, bias1, h1b[tau & 1], h2b[tau & 1], h2b[(tau + 1) & 1], tau - 1);
    }
    const f16* h2fin = h2b[(TT + 1) & 1];

    // --- GRU head ---
    gemm_bt_kernel<<<dim3(64, 4), 256, 0, stream>>>(mean_emb, fc_mean_W, mf, BB, HH, 256, fc_mean_b, nullptr, 1);
    build_gru_feat_kernel<<<(BB * 512) / 256, 256, 0, stream>>>(h2fin, mf, gf);
    gemm_bt_kernel<<<dim3(64, 2), 256, 0, stream>>>(gf, gru_fc_W, out_g, BB, DOUT_, 512, gru_fc_b, nullptr, 0);

    // --- similarity (split-f16 MFMA) + exact top-k threshold ---
    sim_pack_kernel<<<4096, 256, 0, stream>>>(prior, packA, packB);
    sim_mm_kernel<<<dim3(32, 32), 256, 0, stream>>>(packA, packB, sim);
    for (int pass = 0; pass < 3; pass++) {
        hipMemsetAsync(hist, 0, 4096 * 4, stream);
        hist_kernel<<<1024, 256, 0, stream>>>(sim, hist, state, pass);
        scan_hist_kernel<<<1, 256, 0, stream>>>(hist, state, pass);
    }
    degree_kernel<<<BB, 256, 0, stream>>>(sim, state, dinv);

    // --- GCN (MFMA masked aggregation, split-K=4) ---
    gemm_bt_kernel<<<dim3(64, 4), 256, 0, stream>>>(prior, gcn1_W, xws1, BB, HH, 256, nullptr, dinv, 0);
    txp_kernel<<<4096, 256, 0, stream>>>(xws1, xwsT16);
    gcn_mm_kernel<<<dim3(32, 2, 4), 256, 0, stream>>>(sim, xwsT16, state, ps);
    gcn_combine_kernel<<<4096, 256, 0, stream>>>(ps, xws1, dinv, gcn1_b, ph1);
    gemm_bt_kernel<<<dim3(64, 4), 256, 0, stream>>>(ph1, gcn2_W, xws2, BB, HH, 256, nullptr, dinv, 0);
    txp_kernel<<<4096, 256, 0, stream>>>(xws2, xwsT16);
    gcn_mm_kernel<<<dim3(32, 2, 4), 256, 0, stream>>>(sim, xwsT16, state, ps);
    gcn_combine_kernel<<<4096, 256, 0, stream>>>(ps, xws2, dinv, gcn2_b, ph2);
    gemm_bt_kernel<<<dim3(64, 2), 256, 0, stream>>>(ph2, prior_fc_W, out_p, BB, DOUT_, 256, prior_fc_b, nullptr, 0);

    // --- fusion: experts + attention ---
    build_fused_diff_kernel<<<(BB * 256) / 256, 256, 0, stream>>>(out_g, out_p, fusedb, diffb);
    for (int e = 0; e < NEXP_; e++)
        gemm_bt_kernel<<<dim3(64, 2), 256, 0, stream>>>(diffb, expert_W + (long)e * DOUT_ * DOUT_,
                                                        er + (long)e * BB * DOUT_, BB, DOUT_, DOUT_,
                                                        nullptr, nullptr, 0);
    gemm_bt_kernel<<<dim3(64, 2), 256, 0, stream>>>(fusedb, attn1_W, hatt, BB, DOUT_, 256, attn1_b, nullptr, 2);
    final_kernel<<<BB, 128, 0, stream>>>(hatt, attn2_W, attn2_b, er, out_g, out_p, out_pred);
}